// Round 11
// baseline (99.311 us; speedup 1.0000x reference)
//
#include <hip/hip_runtime.h>

#define B_   2
#define N_   512
#define DM_  1024
#define H_   16
#define LAM_ 0.1f

typedef __attribute__((ext_vector_type(8))) short bf16x8;
typedef __attribute__((ext_vector_type(4))) float f32x4;
typedef unsigned short ush;
struct ush4 { ush x, y, z, w; };
struct uint2s { unsigned x, y; };

__device__ inline ush f2bf(float v) {
    union { float f; unsigned u; } c; c.f = v;
    unsigned r = c.u + 0x7FFF + ((c.u >> 16) & 1);
    return (ush)(r >> 16);
}
__device__ inline float bf2f(ush b) {
    union { float f; unsigned u; } c; c.u = ((unsigned)b) << 16; return c.f;
}
__device__ inline f32x4 mfma16(bf16x8 a, bf16x8 b, f32x4 c) {
    return __builtin_amdgcn_mfma_f32_16x16x32_bf16(a, b, c, 0, 0, 0);
}
// jnp.argmax semantics (first max wins); uniform -> scalar loads
__device__ inline int sel_of(const float* __restrict__ lg) {
    float b = lg[0]; int s = 0;
    if (lg[1] > b) { b = lg[1]; s = 1; }
    if (lg[2] > b) { b = lg[2]; s = 2; }
    if (lg[3] > b) { b = lg[3]; s = 3; }
    return s;
}

// V^T padded stride per head: data rows [0,hd), ones row at hd, zeros to PT
template<int HD> struct vpad_t { static constexpr int PT = (HD >= 16) ? HD + 16 : 16; };

// ---------------------------------------------------------------------------
// fused prep. Region map (256-thread blocks):
//   [0,    1024): x+pe -> bf16 hi/lo, float4-vectorized
//   [1024, 1792): wqkv transpose, 64x64 LDS tiles
//   [1792, 2048): wo transpose, 64x64 LDS tiles
//   [2048, 3072): V^T pad fill (ones row at hd, zeros above)
// ---------------------------------------------------------------------------
template<int D>
__device__ void prep_wt_tile(int bT, int tid, const float* __restrict__ w,
                             ush* __restrict__ wh, ush* __restrict__ wl,
                             float (*lds)[65]) {
    constexpr int ds = DM_ / D;
    constexpr int tpr = 3 * ds / 64;
    constexpr int tpc = ds / 64;
    constexpr int tpd = tpr * tpc;
    if (bT >= D * tpd) return;
    const int d = bT / tpd, rem = bT % tpd;
    const int tr = rem / tpr, tc = rem % tpr;
    const float* src = w + (size_t)d * ds * 3 * ds;
    ush* dsth = wh + (size_t)d * 3 * ds * ds;
    ush* dstl = wl + (size_t)d * 3 * ds * ds;
    const int c = tid & 63, r0 = tid >> 6;
    #pragma unroll
    for (int j = 0; j < 16; ++j) {
        const int r = j * 4 + r0;
        lds[r][c] = src[(size_t)(tr * 64 + r) * (3 * ds) + tc * 64 + c];
    }
    __syncthreads();
    #pragma unroll
    for (int j = 0; j < 16; ++j) {
        const int r = j * 4 + r0;
        const float v = lds[c][r];
        const size_t o = (size_t)(tc * 64 + r) * ds + tr * 64 + c;
        const ush h = f2bf(v);
        dsth[o] = h; dstl[o] = f2bf(v - bf2f(h));
    }
}
template<int D>
__device__ void prep_vpad(int bT, int tid, ush* __restrict__ Vth, ush* __restrict__ Vtl) {
    constexpr int ds = DM_ / D, hd = ds / H_;
    constexpr int PT = vpad_t<hd>::PT;
    constexpr int NH = B_ * D * H_;
    constexpr int PR = PT - hd;
    constexpr int TOT = NH * PR * (N_ / 4);
    const int g = bT * 256 + tid;
    if (g >= TOT) return;
    constexpr int perh = PR * (N_ / 4);
    const int head = g / perh, rem = g % perh;
    const int r = hd + rem / (N_ / 4), n4 = (rem % (N_ / 4)) * 4;
    const size_t o = ((size_t)head * PT + r) * N_ + n4;
    const ush one = (r == hd) ? (ush)0x3F80 : (ush)0;
    ush4 hv; hv.x = one; hv.y = one; hv.z = one; hv.w = one;
    ush4 zv; zv.x = 0; zv.y = 0; zv.z = 0; zv.w = 0;
    *(ush4*)&Vth[o] = hv;
    *(ush4*)&Vtl[o] = zv;
}
__global__ __launch_bounds__(256) void k_prep(
        const float* __restrict__ logits, const float* __restrict__ x,
        const float* __restrict__ pe0, const float* __restrict__ pe1,
        const float* __restrict__ pe2, const float* __restrict__ pe3,
        const float* __restrict__ w0, const float* __restrict__ w1,
        const float* __restrict__ w2, const float* __restrict__ w3,
        const float* __restrict__ wo0, const float* __restrict__ wo1,
        const float* __restrict__ wo2, const float* __restrict__ wo3,
        ush* __restrict__ xh, ush* __restrict__ xl,
        ush* __restrict__ wqh, ush* __restrict__ wql,
        ush* __restrict__ woh, ush* __restrict__ wol,
        ush* __restrict__ Vth, ush* __restrict__ Vtl) {
    __shared__ float lds[64][65];
    const int s = sel_of(logits);
    const int bid = blockIdx.x, tid = threadIdx.x;
    if (bid < 1024) {
        const float* pe = (s == 0) ? pe0 : (s == 1) ? pe1 : (s == 2) ? pe2 : pe3;
        const size_t i0 = ((size_t)bid * 256 + tid) * 4;
        const float4 xv = *(const float4*)&x[i0];
        const float4 pv = *(const float4*)&pe[i0 & ((size_t)N_ * DM_ - 1)];
        ush4 h4, l4;
        float v;
        v = xv.x + pv.x; h4.x = f2bf(v); l4.x = f2bf(v - bf2f(h4.x));
        v = xv.y + pv.y; h4.y = f2bf(v); l4.y = f2bf(v - bf2f(h4.y));
        v = xv.z + pv.z; h4.z = f2bf(v); l4.z = f2bf(v - bf2f(h4.z));
        v = xv.w + pv.w; h4.w = f2bf(v); l4.w = f2bf(v - bf2f(h4.w));
        *(ush4*)&xh[i0] = h4;
        *(ush4*)&xl[i0] = l4;
    } else if (bid < 1792) {
        const int bT = bid - 1024;
        switch (s) {
            case 0: prep_wt_tile<1>(bT, tid, w0, wqh, wql, lds); break;
            case 1: prep_wt_tile<2>(bT, tid, w1, wqh, wql, lds); break;
            case 2: prep_wt_tile<4>(bT, tid, w2, wqh, wql, lds); break;
            case 3: prep_wt_tile<8>(bT, tid, w3, wqh, wql, lds); break;
        }
    } else if (bid < 2048) {
        const float* w = (s == 0) ? wo0 : (s == 1) ? wo1 : (s == 2) ? wo2 : wo3;
        const int bT = bid - 1792;
        const int tr = bT >> 4, tc = bT & 15;
        const int c = tid & 63, r0 = tid >> 6;
        #pragma unroll
        for (int j = 0; j < 16; ++j) {
            const int r = j * 4 + r0;
            lds[r][c] = w[(size_t)(tr * 64 + r) * DM_ + tc * 64 + c];
        }
        __syncthreads();
        #pragma unroll
        for (int j = 0; j < 16; ++j) {
            const int r = j * 4 + r0;
            const float v = lds[c][r];
            const size_t o = (size_t)(tc * 64 + r) * DM_ + tr * 64 + c;
            const ush h = f2bf(v);
            woh[o] = h; wol[o] = f2bf(v - bf2f(h));
        }
    } else {
        const int bT = bid - 2048;
        switch (s) {
            case 0: prep_vpad<1>(bT, tid, Vth, Vtl); break;
            case 1: prep_vpad<2>(bT, tid, Vth, Vtl); break;
            case 2: prep_vpad<4>(bT, tid, Vth, Vtl); break;
            case 3: prep_vpad<8>(bT, tid, Vth, Vtl); break;
        }
    }
}

// ---------------------------------------------------------------------------
// Split-bf16 MFMA GEMM core (64x64 tile, BK=32, 4 waves) — used by k_qkv
// ---------------------------------------------------------------------------
template<int KD>
__device__ void gemm_core(const ush* __restrict__ Ah, const ush* __restrict__ Al, int lda,
                          const ush* __restrict__ Bh, const ush* __restrict__ Bl, int ldb,
                          int row0, int col0, int tid, ush* lds, f32x4 acc[2][2]) {
    ush* lAh = lds; ush* lAl = lds + 2560; ush* lBh = lds + 5120; ush* lBl = lds + 7680;
    const int srow = tid >> 2, scg = tid & 3;
    const int lane = tid & 63, w = tid >> 6;
    const int wm = w >> 1, wn = w & 1;
    const int lr = lane & 15, lb = lane >> 4;

    for (int k0 = 0; k0 < KD; k0 += 32) {
        *(bf16x8*)&lAh[srow * 40 + scg * 8] =
            *(const bf16x8*)&Ah[(size_t)(row0 + srow) * lda + k0 + scg * 8];
        *(bf16x8*)&lAl[srow * 40 + scg * 8] =
            *(const bf16x8*)&Al[(size_t)(row0 + srow) * lda + k0 + scg * 8];
        *(bf16x8*)&lBh[srow * 40 + scg * 8] =
            *(const bf16x8*)&Bh[(size_t)(col0 + srow) * ldb + k0 + scg * 8];
        *(bf16x8*)&lBl[srow * 40 + scg * 8] =
            *(const bf16x8*)&Bl[(size_t)(col0 + srow) * ldb + k0 + scg * 8];
        __syncthreads();
        bf16x8 ah[2], al[2], bh[2], bl[2];
        #pragma unroll
        for (int mg = 0; mg < 2; ++mg) {
            const int r = wm * 32 + mg * 16 + lr;
            ah[mg] = *(const bf16x8*)&lAh[r * 40 + lb * 8];
            al[mg] = *(const bf16x8*)&lAl[r * 40 + lb * 8];
        }
        #pragma unroll
        for (int ng = 0; ng < 2; ++ng) {
            const int r = wn * 32 + ng * 16 + lr;
            bh[ng] = *(const bf16x8*)&lBh[r * 40 + lb * 8];
            bl[ng] = *(const bf16x8*)&lBl[r * 40 + lb * 8];
        }
        #pragma unroll
        for (int mg = 0; mg < 2; ++mg)
            #pragma unroll
            for (int ng = 0; ng < 2; ++ng) {
                acc[mg][ng] = mfma16(ah[mg], bh[ng], acc[mg][ng]);
                acc[mg][ng] = mfma16(al[mg], bh[ng], acc[mg][ng]);
                acc[mg][ng] = mfma16(ah[mg], bl[ng], acc[mg][ng]);
            }
        __syncthreads();
    }
}

// ---------------------------------------------------------------------------
// qkv GEMM; epilogue: Q (PRE-SCALED by log2e/sqrt(hd)) and K as bf16 hi/lo
// [head][n][hd]; V TRANSPOSED bf16 hi/lo into padded [head][PT][n]
// ---------------------------------------------------------------------------
template<int D>
__device__ void qkv_body(int bid, int tid,
                         const ush* __restrict__ xh, const ush* __restrict__ xl,
                         const ush* __restrict__ wh, const ush* __restrict__ wl,
                         ush* __restrict__ Qh, ush* __restrict__ Ql,
                         ush* __restrict__ Kh, ush* __restrict__ Kl,
                         ush* __restrict__ Vth, ush* __restrict__ Vtl, ush* lds) {
    constexpr int ds = DM_ / D;
    constexpr int hd = ds / H_;
    constexpr int PT = vpad_t<hd>::PT;
    constexpr int nx = 3 * ds / 64;
    const int bx = bid % nx, by = (bid / nx) & 7, bz = bid / (nx * 8);
    const int b = bz / D, d = bz % D;
    const int row0 = by * 64, col0 = bx * 64;
    const float SCQ = 1.44269504f * rsqrtf((float)hd);

    f32x4 acc[2][2] = {};
    gemm_core<ds>(xh + (size_t)b * N_ * DM_ + d * ds, xl + (size_t)b * N_ * DM_ + d * ds, DM_,
                  wh + (size_t)d * 3 * ds * ds, wl + (size_t)d * 3 * ds * ds, ds,
                  row0, col0, tid, lds, acc);

    const int lane = tid & 63, w = tid >> 6;
    const int wm = w >> 1, wn = w & 1;
    const int lr = lane & 15, lb = lane >> 4;
    #pragma unroll
    for (int mg = 0; mg < 2; ++mg)
        #pragma unroll
        for (int ng = 0; ng < 2; ++ng) {
            const int n0 = row0 + wm * 32 + mg * 16 + lb * 4;
            const int e  = col0 + wn * 32 + ng * 16 + lr;
            const int part = e / ds, ep = e % ds;
            const int h = ep / hd, t = ep % hd;
            const size_t head = ((size_t)b * D + d) * H_ + h;
            if (part == 2) {
                ush4 h4, l4;
                const float v0 = acc[mg][ng][0], v1 = acc[mg][ng][1];
                const float v2 = acc[mg][ng][2], v3 = acc[mg][ng][3];
                h4.x = f2bf(v0); l4.x = f2bf(v0 - bf2f(h4.x));
                h4.y = f2bf(v1); l4.y = f2bf(v1 - bf2f(h4.y));
                h4.z = f2bf(v2); l4.z = f2bf(v2 - bf2f(h4.z));
                h4.w = f2bf(v3); l4.w = f2bf(v3 - bf2f(h4.w));
                const size_t o = (head * PT + t) * N_ + n0;
                *(ush4*)&Vth[o] = h4;
                *(ush4*)&Vtl[o] = l4;
            } else {
                #pragma unroll
                for (int i = 0; i < 4; ++i) {
                    const size_t o = (head * N_ + n0 + i) * hd + t;
                    float v = acc[mg][ng][i];
                    if (part == 0) v *= SCQ;
                    const ush hh = f2bf(v), ll = f2bf(v - bf2f(hh));
                    if (part == 0) { Qh[o] = hh; Ql[o] = ll; }
                    else           { Kh[o] = hh; Kl[o] = ll; }
                }
            }
        }
}
__global__ __launch_bounds__(256) void k_qkv(
        const float* __restrict__ logits,
        const ush* __restrict__ xh, const ush* __restrict__ xl,
        const ush* __restrict__ wh, const ush* __restrict__ wl,
        ush* __restrict__ Qh, ush* __restrict__ Ql,
        ush* __restrict__ Kh, ush* __restrict__ Kl,
        ush* __restrict__ Vth, ush* __restrict__ Vtl) {
    __shared__ ush lds[4 * 2560];
    const int bid = blockIdx.x, tid = threadIdx.x;
    switch (sel_of(logits)) {
        case 0: qkv_body<1>(bid, tid, xh, xl, wh, wl, Qh, Ql, Kh, Kl, Vth, Vtl, lds); break;
        case 1: qkv_body<2>(bid, tid, xh, xl, wh, wl, Qh, Ql, Kh, Kl, Vth, Vtl, lds); break;
        case 2: qkv_body<4>(bid, tid, xh, xl, wh, wl, Qh, Ql, Kh, Kl, Vth, Vtl, lds); break;
        case 3: qkv_body<8>(bid, tid, xh, xl, wh, wl, Qh, Ql, Kh, Kl, Vth, Vtl, lds); break;
    }
}

// ---------------------------------------------------------------------------
// MFMA attention v8: per-D kernels; block = 4 waves = 2 q-tiles x 2 k-halves.
// Wave: 16 q-rows x 256 k-cols in 8 chunks of 32. m=0 softmax via exp2 with
// ring-bias LDS TABLE (wtab) and pre-scaled Q; denominator = PV ones-column;
// cross-half combine via conflict-free LDS + 1 barrier.
// ---------------------------------------------------------------------------
template<int D>
__device__ void attn_dev(int bid, int tid,
        const ush* __restrict__ Qh, const ush* __restrict__ Ql,
        const ush* __restrict__ Kh, const ush* __restrict__ Kl,
        const ush* __restrict__ Vth, const ush* __restrict__ Vtl,
        float* __restrict__ O, ush* Pall, float* wtab, float* comb) {
    constexpr int ds = DM_ / D, hd = ds / H_;
    constexpr int CH  = (hd >= 64) ? 2 : 1;
    constexpr int NTP = (hd >= 16) ? hd / 16 + 1 : 1;
    constexpr int PT  = vpad_t<hd>::PT;
    constexpr int TL  = hd / 16;
    constexpr int LRL = hd % 16;
    constexpr int NBLK = B_ * D * H_ * 16;   // 2 q-tiles per block
    const float RB2 = LAM_ * (2.0f / N_) * 1.44269504f;

    // ring-bias table: wtab[j] = exp2(-RB2 * ring(j)), padded 4 for wrap
    for (int j = tid; j < 516; j += 256) {
        const int jj = j & 511;
        const int ring = (jj < 512 - jj) ? jj : 512 - jj;
        wtab[j] = exp2f(-RB2 * (float)ring);
    }
    __syncthreads();

    const int bidr = (bid & 7) * (NBLK / 8) + (bid >> 3);
    const int w = tid >> 6, lane = tid & 63;
    const int pair = w >> 1, half = w & 1;
    const int gt = bidr * 2 + pair;          // global q-tile
    const int head = gt >> 5, qt = gt & 31;
    const int h = head % H_, d = (head / H_) % D, b = head / (H_ * D);
    const int q0 = qt * 16;
    const size_t hbq = (size_t)head * N_ * hd;
    const size_t hbv = (size_t)head * PT * N_;
    const int lr = lane & 15, lb = lane >> 4;
    ush* Pc = Pall + w * 16 * 40;            // [16 rows][40 ush] wave-private
    const bf16x8 z8 = {0, 0, 0, 0, 0, 0, 0, 0};

    // Q fragment (B-operand), already scaled by log2e/sqrt(hd)
    bf16x8 qah[CH], qal[CH];
    #pragma unroll
    for (int c = 0; c < CH; ++c) {
        const int k0 = c * 32 + lb * 8;
        bf16x8 vh = z8, vl = z8;
        if (k0 < hd) {
            const size_t o = hbq + (size_t)(q0 + lr) * hd + k0;
            vh = *(const bf16x8*)&Qh[o];
            vl = *(const bf16x8*)&Ql[o];
        }
        qah[c] = vh; qal[c] = vl;
    }

    const int q = q0 + lr;
    f32x4 acc2[NTP];
    #pragma unroll
    for (int tt = 0; tt < NTP; ++tt) acc2[tt] = (f32x4){0.f, 0.f, 0.f, 0.f};

    for (int ck = half * 8; ck < half * 8 + 8; ++ck) {
        const int col0 = ck * 32;

        // S^T = K Q^T for 2 tiles (32 k-cols), already log2-scaled
        f32x4 s0 = {0.f, 0.f, 0.f, 0.f}, s1 = {0.f, 0.f, 0.f, 0.f};
        #pragma unroll
        for (int c = 0; c < CH; ++c) {
            const int k0 = c * 32 + lb * 8;
            bf16x8 k0h = z8, k0l = z8, k1h = z8, k1l = z8;
            if (k0 < hd) {
                const size_t o0 = hbq + (size_t)(col0 + lr) * hd + k0;
                const size_t o1 = hbq + (size_t)(col0 + 16 + lr) * hd + k0;
                k0h = *(const bf16x8*)&Kh[o0]; k0l = *(const bf16x8*)&Kl[o0];
                k1h = *(const bf16x8*)&Kh[o1]; k1l = *(const bf16x8*)&Kl[o1];
            }
            s0 = mfma16(k0h, qah[c], s0);
            s0 = mfma16(k0l, qah[c], s0);
            s0 = mfma16(k0h, qal[c], s0);
            s1 = mfma16(k1h, qah[c], s1);
            s1 = mfma16(k1l, qah[c], s1);
            s1 = mfma16(k1h, qal[c], s1);
        }

        // p = exp2(s) * wtab[(k-q)&511]; packed bf16 -> LDS
        #pragma unroll
        for (int t = 0; t < 2; ++t) {
            const f32x4 sv = t ? s1 : s0;
            const int kbase = col0 + t * 16 + lb * 4;
            const int j0 = (kbase - q) & 511;
            float p[4];
            #pragma unroll
            for (int i = 0; i < 4; ++i)
                p[i] = exp2f(sv[i]) * wtab[j0 + i];
            unsigned pk0, pk1;
            asm("v_cvt_pk_bf16_f32 %0, %1, %2" : "=v"(pk0) : "v"(p[0]), "v"(p[1]));
            asm("v_cvt_pk_bf16_f32 %0, %1, %2" : "=v"(pk1) : "v"(p[2]), "v"(p[3]));
            uint2s pv; pv.x = pk0; pv.y = pk1;
            *(uint2s*)((char*)Pc + lr * 80 + t * 32 + lb * 8) = pv;
        }

        // PV for this 32-col chunk (in-wave lgkmcnt dependency, no barrier)
        const bf16x8 pa = *(const bf16x8*)((const char*)Pc + lr * 80 + lb * 16);
        #pragma unroll
        for (int tt = 0; tt < NTP; ++tt) {
            const size_t o = hbv + (size_t)(tt * 16 + lr) * N_ + col0 + lb * 8;
            const bf16x8 vh8 = *(const bf16x8*)&Vth[o];
            const bf16x8 vl8 = *(const bf16x8*)&Vtl[o];
            acc2[tt] = mfma16(pa, vh8, acc2[tt]);
            acc2[tt] = mfma16(pa, vl8, acc2[tt]);
        }
    }

    // cross-half combine (conflict-free [tt][i][lane] layout), 1 barrier
    if (half) {
        #pragma unroll
        for (int tt = 0; tt < NTP; ++tt)
            #pragma unroll
            for (int i = 0; i < 4; ++i)
                comb[((pair * NTP + tt) * 4 + i) * 64 + lane] = acc2[tt][i];
    }
    __syncthreads();
    if (!half) {
        #pragma unroll
        for (int tt = 0; tt < NTP; ++tt)
            #pragma unroll
            for (int i = 0; i < 4; ++i)
                acc2[tt][i] += comb[((pair * NTP + tt) * 4 + i) * 64 + lane];
        // l = ones-column of summed accumulator; redistribute per output row
        float linv[4];
        #pragma unroll
        for (int i = 0; i < 4; ++i)
            linv[i] = 1.0f / __shfl(acc2[TL][i], (lane & 48) | LRL);
        #pragma unroll
        for (int tt = 0; tt < NTP; ++tt)
            #pragma unroll
            for (int i = 0; i < 4; ++i) {
                const int rn = q0 + lb * 4 + i;
                const int tc = tt * 16 + lr;
                if (tc < hd)
                    O[((size_t)b * N_ + rn) * DM_ + d * ds + h * hd + tc] = acc2[tt][i] * linv[i];
            }
    }
}
#define DEF_ATTN(NAME, DD, BR)                                                \
__global__ __launch_bounds__(256) void NAME(                                  \
        const float* __restrict__ logits,                                     \
        const ush* __restrict__ Qh, const ush* __restrict__ Ql,               \
        const ush* __restrict__ Kh, const ush* __restrict__ Kl,               \
        const ush* __restrict__ Vth, const ush* __restrict__ Vtl,             \
        float* __restrict__ O) {                                              \
    __shared__ __align__(16) ush Pc[4 * 16 * 40];                             \
    __shared__ float wtab[516];                                               \
    __shared__ float comb[2560];                                              \
    if (sel_of(logits) != BR) return;                                         \
    attn_dev<DD>(blockIdx.x, threadIdx.x, Qh, Ql, Kh, Kl, Vth, Vtl, O,        \
                 Pc, wtab, comb);                                             \
}
DEF_ATTN(k_attn_1, 1, 0)
DEF_ATTN(k_attn_2, 2, 1)
DEF_ATTN(k_attn_4, 4, 2)
DEF_ATTN(k_attn_8, 8, 3)

// ---------------------------------------------------------------------------
// depth mix: F = einsum(mix, O) -> bf16 hi/lo
// ---------------------------------------------------------------------------
template<int D>
__device__ void mix_body(int bid, int tid, const float* __restrict__ fu,
                         const float* __restrict__ fv, const float* __restrict__ O,
                         ush* __restrict__ Fh, ush* __restrict__ Fl, float* mixs) {
    constexpr int ds = DM_ / D;
    constexpr int R = (D / 4 > 0) ? (D / 4) : 1;
    if (tid < D * D) {
        const int d = tid / D, f = tid % D;
        float m = 0.f;
        #pragma unroll
        for (int rr = 0; rr < R; ++rr) m += fu[d * R + rr] * fv[rr * D + f];
        mixs[tid] = m;
    }
    __syncthreads();
    const size_t idx = (size_t)bid * 256 + tid;
    const int dm = (int)(idx % DM_);
    const size_t bn = idx / DM_;
    const int d = dm / ds, s0 = dm % ds;
    const float* Ob = O + bn * DM_ + s0;
    float acc = 0.f;
    #pragma unroll
    for (int f = 0; f < D; ++f) acc += mixs[d * D + f] * Ob[(size_t)f * ds];
    const ush hh = f2bf(acc);
    Fh[idx] = hh; Fl[idx] = f2bf(acc - bf2f(hh));
}
__global__ __launch_bounds__(256) void k_mix(
        const float* __restrict__ logits,
        const float* __restrict__ fu0, const float* __restrict__ fv0,
        const float* __restrict__ fu1, const float* __restrict__ fv1,
        const float* __restrict__ fu2, const float* __restrict__ fv2,
        const float* __restrict__ fu3, const float* __restrict__ fv3,
        const float* __restrict__ O, ush* __restrict__ Fh, ush* __restrict__ Fl) {
    __shared__ float mixs[64];
    const int bid = blockIdx.x, tid = threadIdx.x;
    switch (sel_of(logits)) {
        case 0: mix_body<1>(bid, tid, fu0, fv0, O, Fh, Fl, mixs); break;
        case 1: mix_body<2>(bid, tid, fu1, fv1, O, Fh, Fl, mixs); break;
        case 2: mix_body<4>(bid, tid, fu2, fv2, O, Fh, Fl, mixs); break;
        case 3: mix_body<8>(bid, tid, fu3, fv3, O, Fh, Fl, mixs); break;
    }
}

// ---------------------------------------------------------------------------
// out = F @ wo — 32x64 tiles, grid 512
// ---------------------------------------------------------------------------
__global__ __launch_bounds__(256) void k_wo(
        const ush* __restrict__ Fh, const ush* __restrict__ Fl,
        const ush* __restrict__ wh, const ush* __restrict__ wl,
        float* __restrict__ out) {
    __shared__ ush lA[2][32 * 40];
    __shared__ ush lB[2][64 * 40];
    const int tid = threadIdx.x;
    const int bx = blockIdx.x & 15, by = blockIdx.x >> 4;
    const int row0 = by * 32, col0 = bx * 64;
    const int lane = tid & 63, w = tid >> 6;
    const int wq = w >> 1, wn = w & 1;
    const int lr = lane & 15, lb = lane >> 4;
    f32x4 acc[2] = {};

    for (int k0 = 0; k0 < DM_; k0 += 32) {
        {
            const int half = tid >> 7, t2 = tid & 127;
            const int srow = t2 >> 2, scg = t2 & 3;
            const ush* src = half ? Fl : Fh;
            *(bf16x8*)&lA[half][srow * 40 + scg * 8] =
                *(const bf16x8*)&src[(size_t)(row0 + srow) * DM_ + k0 + scg * 8];
        }
        {
            const int srow = tid >> 2, scg = tid & 3;
            *(bf16x8*)&lB[0][srow * 40 + scg * 8] =
                *(const bf16x8*)&wh[(size_t)(col0 + srow) * DM_ + k0 + scg * 8];
            *(bf16x8*)&lB[1][srow * 40 + scg * 8] =
                *(const bf16x8*)&wl[(size_t)(col0 + srow) * DM_ + k0 + scg * 8];
        }
        __syncthreads();
        const int ar = wq * 16 + lr;
        const bf16x8 ah = *(const bf16x8*)&lA[0][ar * 40 + lb * 8];
        const bf16x8 al = *(const bf16x8*)&lA[1][ar * 40 + lb * 8];
        #pragma unroll
        for (int ng = 0; ng < 2; ++ng) {
            const int br = wn * 32 + ng * 16 + lr;
            const bf16x8 bh = *(const bf16x8*)&lB[0][br * 40 + lb * 8];
            const bf16x8 bl = *(const bf16x8*)&lB[1][br * 40 + lb * 8];
            acc[ng] = mfma16(ah, bh, acc[ng]);
            acc[ng] = mfma16(al, bh, acc[ng]);
            acc[ng] = mfma16(ah, bl, acc[ng]);
        }
        __syncthreads();
    }
    #pragma unroll
    for (int ng = 0; ng < 2; ++ng)
        #pragma unroll
        for (int i = 0; i < 4; ++i) {
            const int r = row0 + wq * 16 + lb * 4 + i;
            const int c = col0 + wn * 32 + ng * 16 + lr;
            out[(size_t)r * DM_ + c] = acc[ng][i];
        }
}

// ---------------------------------------------------------------------------
extern "C" void kernel_launch(void* const* d_in, const int* in_sizes, int n_in,
                              void* d_out, int out_size, void* d_ws, size_t ws_size,
                              hipStream_t stream) {
    const float* x      = (const float*)d_in[0];
    const float* logits = (const float*)d_in[1];
    float* out = (float*)d_out;

    char* p = (char*)d_ws;
    p += 256;
    const size_t MB = 1024 * 1024;
    ush* Qh = (ush*)p; p += 2 * MB;
    ush* Ql = (ush*)p; p += 2 * MB;
    ush* Kh = (ush*)p; p += 2 * MB;
    ush* Kl = (ush*)p; p += 2 * MB;
    ush* Vth = (ush*)p; p += 4 * MB;           // padded V^T
    ush* Vtl = (ush*)p; p += 4 * MB;
    float* O = (float*)p; p += 4 * MB;
    ush* xh = (ush*)p; p += 2 * MB;
    ush* xl = (ush*)p; p += 2 * MB;
    ush* wqh = (ush*)p; p += 6 * MB;
    ush* wql = (ush*)p; p += 6 * MB;
    ush* woh = (ush*)p; p += 2 * MB;
    ush* wol = (ush*)p; p += 2 * MB;
    ush* Fh = xh, *Fl = xl;   // k_mix writes after k_qkv consumed xh/xl

    k_prep<<<dim3(3072), dim3(256), 0, stream>>>(
        logits, x,
        (const float*)d_in[2], (const float*)d_in[7],
        (const float*)d_in[12], (const float*)d_in[17],
        (const float*)d_in[3], (const float*)d_in[8],
        (const float*)d_in[13], (const float*)d_in[18],
        (const float*)d_in[4], (const float*)d_in[9],
        (const float*)d_in[14], (const float*)d_in[19],
        xh, xl, wqh, wql, woh, wol, Vth, Vtl);
    k_qkv<<<dim3(768), dim3(256), 0, stream>>>(logits, xh, xl, wqh, wql,
                                               Qh, Ql, Kh, Kl, Vth, Vtl);
    k_attn_1<<<dim3(512),  dim3(256), 0, stream>>>(logits, Qh, Ql, Kh, Kl, Vth, Vtl, O);
    k_attn_2<<<dim3(1024), dim3(256), 0, stream>>>(logits, Qh, Ql, Kh, Kl, Vth, Vtl, O);
    k_attn_4<<<dim3(2048), dim3(256), 0, stream>>>(logits, Qh, Ql, Kh, Kl, Vth, Vtl, O);
    k_attn_8<<<dim3(4096), dim3(256), 0, stream>>>(logits, Qh, Ql, Kh, Kl, Vth, Vtl, O);
    k_mix<<<dim3(B_ * N_ * DM_ / 256), dim3(256), 0, stream>>>(
        logits,
        (const float*)d_in[5],  (const float*)d_in[6],
        (const float*)d_in[10], (const float*)d_in[11],
        (const float*)d_in[15], (const float*)d_in[16],
        (const float*)d_in[20], (const float*)d_in[21],
        O, Fh, Fl);
    k_wo<<<dim3(512), dim3(256), 0, stream>>>(Fh, Fl, woh, wol, out);
}

// Round 12
// 96.027 us; speedup vs baseline: 1.0342x; 1.0342x over previous
//
#include <hip/hip_runtime.h>

#define B_   2
#define N_   512
#define DM_  1024
#define H_   16
#define LAM_ 0.1f

typedef __attribute__((ext_vector_type(8))) short bf16x8;
typedef __attribute__((ext_vector_type(4))) float f32x4;
typedef unsigned short ush;
struct ush4 { ush x, y, z, w; };
struct uint2s { unsigned x, y; };

__device__ inline ush f2bf(float v) {
    union { float f; unsigned u; } c; c.f = v;
    unsigned r = c.u + 0x7FFF + ((c.u >> 16) & 1);
    return (ush)(r >> 16);
}
__device__ inline float bf2f(ush b) {
    union { float f; unsigned u; } c; c.u = ((unsigned)b) << 16; return c.f;
}
__device__ inline f32x4 mfma16(bf16x8 a, bf16x8 b, f32x4 c) {
    return __builtin_amdgcn_mfma_f32_16x16x32_bf16(a, b, c, 0, 0, 0);
}
// jnp.argmax semantics (first max wins); uniform -> scalar loads
__device__ inline int sel_of(const float* __restrict__ lg) {
    float b = lg[0]; int s = 0;
    if (lg[1] > b) { b = lg[1]; s = 1; }
    if (lg[2] > b) { b = lg[2]; s = 2; }
    if (lg[3] > b) { b = lg[3]; s = 3; }
    return s;
}

// V^T padded stride per head: data rows [0,hd), ones row at hd, zeros to PT
template<int HD> struct vpad_t { static constexpr int PT = (HD >= 16) ? HD + 16 : 16; };

// ---------------------------------------------------------------------------
// fused prep. Region map (256-thread blocks):
//   [0,    1024): x+pe -> bf16 hi/lo, float4-vectorized
//   [1024, 1792): wqkv transpose, 64x64 LDS tiles
//   [1792, 2048): wo transpose, 64x64 LDS tiles
//   [2048, 3072): V^T pad fill (ones row at hd, zeros above)
// ---------------------------------------------------------------------------
template<int D>
__device__ void prep_wt_tile(int bT, int tid, const float* __restrict__ w,
                             ush* __restrict__ wh, ush* __restrict__ wl,
                             float (*lds)[65]) {
    constexpr int ds = DM_ / D;
    constexpr int tpr = 3 * ds / 64;
    constexpr int tpc = ds / 64;
    constexpr int tpd = tpr * tpc;
    if (bT >= D * tpd) return;
    const int d = bT / tpd, rem = bT % tpd;
    const int tr = rem / tpr, tc = rem % tpr;
    const float* src = w + (size_t)d * ds * 3 * ds;
    ush* dsth = wh + (size_t)d * 3 * ds * ds;
    ush* dstl = wl + (size_t)d * 3 * ds * ds;
    const int c = tid & 63, r0 = tid >> 6;
    #pragma unroll
    for (int j = 0; j < 16; ++j) {
        const int r = j * 4 + r0;
        lds[r][c] = src[(size_t)(tr * 64 + r) * (3 * ds) + tc * 64 + c];
    }
    __syncthreads();
    #pragma unroll
    for (int j = 0; j < 16; ++j) {
        const int r = j * 4 + r0;
        const float v = lds[c][r];
        const size_t o = (size_t)(tc * 64 + r) * ds + tr * 64 + c;
        const ush h = f2bf(v);
        dsth[o] = h; dstl[o] = f2bf(v - bf2f(h));
    }
}
template<int D>
__device__ void prep_vpad(int bT, int tid, ush* __restrict__ Vth, ush* __restrict__ Vtl) {
    constexpr int ds = DM_ / D, hd = ds / H_;
    constexpr int PT = vpad_t<hd>::PT;
    constexpr int NH = B_ * D * H_;
    constexpr int PR = PT - hd;
    constexpr int TOT = NH * PR * (N_ / 4);
    const int g = bT * 256 + tid;
    if (g >= TOT) return;
    constexpr int perh = PR * (N_ / 4);
    const int head = g / perh, rem = g % perh;
    const int r = hd + rem / (N_ / 4), n4 = (rem % (N_ / 4)) * 4;
    const size_t o = ((size_t)head * PT + r) * N_ + n4;
    const ush one = (r == hd) ? (ush)0x3F80 : (ush)0;
    ush4 hv; hv.x = one; hv.y = one; hv.z = one; hv.w = one;
    ush4 zv; zv.x = 0; zv.y = 0; zv.z = 0; zv.w = 0;
    *(ush4*)&Vth[o] = hv;
    *(ush4*)&Vtl[o] = zv;
}
__global__ __launch_bounds__(256) void k_prep(
        const float* __restrict__ logits, const float* __restrict__ x,
        const float* __restrict__ pe0, const float* __restrict__ pe1,
        const float* __restrict__ pe2, const float* __restrict__ pe3,
        const float* __restrict__ w0, const float* __restrict__ w1,
        const float* __restrict__ w2, const float* __restrict__ w3,
        const float* __restrict__ wo0, const float* __restrict__ wo1,
        const float* __restrict__ wo2, const float* __restrict__ wo3,
        ush* __restrict__ xh, ush* __restrict__ xl,
        ush* __restrict__ wqh, ush* __restrict__ wql,
        ush* __restrict__ woh, ush* __restrict__ wol,
        ush* __restrict__ Vth, ush* __restrict__ Vtl) {
    __shared__ float lds[64][65];
    const int s = sel_of(logits);
    const int bid = blockIdx.x, tid = threadIdx.x;
    if (bid < 1024) {
        const float* pe = (s == 0) ? pe0 : (s == 1) ? pe1 : (s == 2) ? pe2 : pe3;
        const size_t i0 = ((size_t)bid * 256 + tid) * 4;
        const float4 xv = *(const float4*)&x[i0];
        const float4 pv = *(const float4*)&pe[i0 & ((size_t)N_ * DM_ - 1)];
        ush4 h4, l4;
        float v;
        v = xv.x + pv.x; h4.x = f2bf(v); l4.x = f2bf(v - bf2f(h4.x));
        v = xv.y + pv.y; h4.y = f2bf(v); l4.y = f2bf(v - bf2f(h4.y));
        v = xv.z + pv.z; h4.z = f2bf(v); l4.z = f2bf(v - bf2f(h4.z));
        v = xv.w + pv.w; h4.w = f2bf(v); l4.w = f2bf(v - bf2f(h4.w));
        *(ush4*)&xh[i0] = h4;
        *(ush4*)&xl[i0] = l4;
    } else if (bid < 1792) {
        const int bT = bid - 1024;
        switch (s) {
            case 0: prep_wt_tile<1>(bT, tid, w0, wqh, wql, lds); break;
            case 1: prep_wt_tile<2>(bT, tid, w1, wqh, wql, lds); break;
            case 2: prep_wt_tile<4>(bT, tid, w2, wqh, wql, lds); break;
            case 3: prep_wt_tile<8>(bT, tid, w3, wqh, wql, lds); break;
        }
    } else if (bid < 2048) {
        const float* w = (s == 0) ? wo0 : (s == 1) ? wo1 : (s == 2) ? wo2 : wo3;
        const int bT = bid - 1792;
        const int tr = bT >> 4, tc = bT & 15;
        const int c = tid & 63, r0 = tid >> 6;
        #pragma unroll
        for (int j = 0; j < 16; ++j) {
            const int r = j * 4 + r0;
            lds[r][c] = w[(size_t)(tr * 64 + r) * DM_ + tc * 64 + c];
        }
        __syncthreads();
        #pragma unroll
        for (int j = 0; j < 16; ++j) {
            const int r = j * 4 + r0;
            const float v = lds[c][r];
            const size_t o = (size_t)(tc * 64 + r) * DM_ + tr * 64 + c;
            const ush h = f2bf(v);
            woh[o] = h; wol[o] = f2bf(v - bf2f(h));
        }
    } else {
        const int bT = bid - 2048;
        switch (s) {
            case 0: prep_vpad<1>(bT, tid, Vth, Vtl); break;
            case 1: prep_vpad<2>(bT, tid, Vth, Vtl); break;
            case 2: prep_vpad<4>(bT, tid, Vth, Vtl); break;
            case 3: prep_vpad<8>(bT, tid, Vth, Vtl); break;
        }
    }
}

// ---------------------------------------------------------------------------
// Split-bf16 MFMA GEMM core (64x64 tile, BK=32, 4 waves) — used by k_qkv
// ---------------------------------------------------------------------------
template<int KD>
__device__ void gemm_core(const ush* __restrict__ Ah, const ush* __restrict__ Al, int lda,
                          const ush* __restrict__ Bh, const ush* __restrict__ Bl, int ldb,
                          int row0, int col0, int tid, ush* lds, f32x4 acc[2][2]) {
    ush* lAh = lds; ush* lAl = lds + 2560; ush* lBh = lds + 5120; ush* lBl = lds + 7680;
    const int srow = tid >> 2, scg = tid & 3;
    const int lane = tid & 63, w = tid >> 6;
    const int wm = w >> 1, wn = w & 1;
    const int lr = lane & 15, lb = lane >> 4;

    for (int k0 = 0; k0 < KD; k0 += 32) {
        *(bf16x8*)&lAh[srow * 40 + scg * 8] =
            *(const bf16x8*)&Ah[(size_t)(row0 + srow) * lda + k0 + scg * 8];
        *(bf16x8*)&lAl[srow * 40 + scg * 8] =
            *(const bf16x8*)&Al[(size_t)(row0 + srow) * lda + k0 + scg * 8];
        *(bf16x8*)&lBh[srow * 40 + scg * 8] =
            *(const bf16x8*)&Bh[(size_t)(col0 + srow) * ldb + k0 + scg * 8];
        *(bf16x8*)&lBl[srow * 40 + scg * 8] =
            *(const bf16x8*)&Bl[(size_t)(col0 + srow) * ldb + k0 + scg * 8];
        __syncthreads();
        bf16x8 ah[2], al[2], bh[2], bl[2];
        #pragma unroll
        for (int mg = 0; mg < 2; ++mg) {
            const int r = wm * 32 + mg * 16 + lr;
            ah[mg] = *(const bf16x8*)&lAh[r * 40 + lb * 8];
            al[mg] = *(const bf16x8*)&lAl[r * 40 + lb * 8];
        }
        #pragma unroll
        for (int ng = 0; ng < 2; ++ng) {
            const int r = wn * 32 + ng * 16 + lr;
            bh[ng] = *(const bf16x8*)&lBh[r * 40 + lb * 8];
            bl[ng] = *(const bf16x8*)&lBl[r * 40 + lb * 8];
        }
        #pragma unroll
        for (int mg = 0; mg < 2; ++mg)
            #pragma unroll
            for (int ng = 0; ng < 2; ++ng) {
                acc[mg][ng] = mfma16(ah[mg], bh[ng], acc[mg][ng]);
                acc[mg][ng] = mfma16(al[mg], bh[ng], acc[mg][ng]);
                acc[mg][ng] = mfma16(ah[mg], bl[ng], acc[mg][ng]);
            }
        __syncthreads();
    }
}

// ---------------------------------------------------------------------------
// qkv GEMM; epilogue: Q (PRE-SCALED by log2e/sqrt(hd)) and K as bf16 hi/lo
// [head][n][hd]; V TRANSPOSED bf16 hi/lo into padded [head][PT][n]
// ---------------------------------------------------------------------------
template<int D>
__device__ void qkv_body(int bid, int tid,
                         const ush* __restrict__ xh, const ush* __restrict__ xl,
                         const ush* __restrict__ wh, const ush* __restrict__ wl,
                         ush* __restrict__ Qh, ush* __restrict__ Ql,
                         ush* __restrict__ Kh, ush* __restrict__ Kl,
                         ush* __restrict__ Vth, ush* __restrict__ Vtl, ush* lds) {
    constexpr int ds = DM_ / D;
    constexpr int hd = ds / H_;
    constexpr int PT = vpad_t<hd>::PT;
    constexpr int nx = 3 * ds / 64;
    const int bx = bid % nx, by = (bid / nx) & 7, bz = bid / (nx * 8);
    const int b = bz / D, d = bz % D;
    const int row0 = by * 64, col0 = bx * 64;
    const float SCQ = 1.44269504f * rsqrtf((float)hd);

    f32x4 acc[2][2] = {};
    gemm_core<ds>(xh + (size_t)b * N_ * DM_ + d * ds, xl + (size_t)b * N_ * DM_ + d * ds, DM_,
                  wh + (size_t)d * 3 * ds * ds, wl + (size_t)d * 3 * ds * ds, ds,
                  row0, col0, tid, lds, acc);

    const int lane = tid & 63, w = tid >> 6;
    const int wm = w >> 1, wn = w & 1;
    const int lr = lane & 15, lb = lane >> 4;
    #pragma unroll
    for (int mg = 0; mg < 2; ++mg)
        #pragma unroll
        for (int ng = 0; ng < 2; ++ng) {
            const int n0 = row0 + wm * 32 + mg * 16 + lb * 4;
            const int e  = col0 + wn * 32 + ng * 16 + lr;
            const int part = e / ds, ep = e % ds;
            const int h = ep / hd, t = ep % hd;
            const size_t head = ((size_t)b * D + d) * H_ + h;
            if (part == 2) {
                ush4 h4, l4;
                const float v0 = acc[mg][ng][0], v1 = acc[mg][ng][1];
                const float v2 = acc[mg][ng][2], v3 = acc[mg][ng][3];
                h4.x = f2bf(v0); l4.x = f2bf(v0 - bf2f(h4.x));
                h4.y = f2bf(v1); l4.y = f2bf(v1 - bf2f(h4.y));
                h4.z = f2bf(v2); l4.z = f2bf(v2 - bf2f(h4.z));
                h4.w = f2bf(v3); l4.w = f2bf(v3 - bf2f(h4.w));
                const size_t o = (head * PT + t) * N_ + n0;
                *(ush4*)&Vth[o] = h4;
                *(ush4*)&Vtl[o] = l4;
            } else {
                #pragma unroll
                for (int i = 0; i < 4; ++i) {
                    const size_t o = (head * N_ + n0 + i) * hd + t;
                    float v = acc[mg][ng][i];
                    if (part == 0) v *= SCQ;
                    const ush hh = f2bf(v), ll = f2bf(v - bf2f(hh));
                    if (part == 0) { Qh[o] = hh; Ql[o] = ll; }
                    else           { Kh[o] = hh; Kl[o] = ll; }
                }
            }
        }
}
__global__ __launch_bounds__(256) void k_qkv(
        const float* __restrict__ logits,
        const ush* __restrict__ xh, const ush* __restrict__ xl,
        const ush* __restrict__ wh, const ush* __restrict__ wl,
        ush* __restrict__ Qh, ush* __restrict__ Ql,
        ush* __restrict__ Kh, ush* __restrict__ Kl,
        ush* __restrict__ Vth, ush* __restrict__ Vtl) {
    __shared__ ush lds[4 * 2560];
    const int bid = blockIdx.x, tid = threadIdx.x;
    switch (sel_of(logits)) {
        case 0: qkv_body<1>(bid, tid, xh, xl, wh, wl, Qh, Ql, Kh, Kl, Vth, Vtl, lds); break;
        case 1: qkv_body<2>(bid, tid, xh, xl, wh, wl, Qh, Ql, Kh, Kl, Vth, Vtl, lds); break;
        case 2: qkv_body<4>(bid, tid, xh, xl, wh, wl, Qh, Ql, Kh, Kl, Vth, Vtl, lds); break;
        case 3: qkv_body<8>(bid, tid, xh, xl, wh, wl, Qh, Ql, Kh, Kl, Vth, Vtl, lds); break;
    }
}

// ---------------------------------------------------------------------------
// MFMA attention v9: per-D kernels; block = 4 waves = 2 q-tiles x 2 k-halves.
// DUAL-STREAM chunk loop: each iteration processes TWO 32-col chunks with
// independent P buffers so QK/loads of one stream hide the exp->LDS->PV
// latency of the other (latency-chain-bound fix, round-11 counters).
// m=0 softmax via exp2 + ring-bias LDS table, pre-scaled Q, denominator =
// PV ones-column; cross-half combine via conflict-free LDS + 1 barrier.
// ---------------------------------------------------------------------------
template<int D>
__device__ void attn_dev(int bid, int tid,
        const ush* __restrict__ Qh, const ush* __restrict__ Ql,
        const ush* __restrict__ Kh, const ush* __restrict__ Kl,
        const ush* __restrict__ Vth, const ush* __restrict__ Vtl,
        float* __restrict__ O, ush* Pall, float* wtab, float* comb) {
    constexpr int ds = DM_ / D, hd = ds / H_;
    constexpr int CH  = (hd >= 64) ? 2 : 1;
    constexpr int NTP = (hd >= 16) ? hd / 16 + 1 : 1;
    constexpr int PT  = vpad_t<hd>::PT;
    constexpr int TL  = hd / 16;
    constexpr int LRL = hd % 16;
    constexpr int NBLK = B_ * D * H_ * 16;   // 2 q-tiles per block
    const float RB2 = LAM_ * (2.0f / N_) * 1.44269504f;

    // ring-bias table: wtab[j] = exp2(-RB2 * ring(j)), padded 4 for wrap
    for (int j = tid; j < 516; j += 256) {
        const int jj = j & 511;
        const int ring = (jj < 512 - jj) ? jj : 512 - jj;
        wtab[j] = exp2f(-RB2 * (float)ring);
    }
    __syncthreads();

    const int bidr = (bid & 7) * (NBLK / 8) + (bid >> 3);
    const int w = tid >> 6, lane = tid & 63;
    const int pair = w >> 1, half = w & 1;
    const int gt = bidr * 2 + pair;          // global q-tile
    const int head = gt >> 5, qt = gt & 31;
    const int h = head % H_, d = (head / H_) % D, b = head / (H_ * D);
    const int q0 = qt * 16;
    const size_t hbq = (size_t)head * N_ * hd;
    const size_t hbv = (size_t)head * PT * N_;
    const int lr = lane & 15, lb = lane >> 4;
    ush* PcA = Pall + w * 1280;              // two 640-ush buffers per wave
    ush* PcB = PcA + 640;
    const bf16x8 z8 = {0, 0, 0, 0, 0, 0, 0, 0};

    // Q fragment (B-operand), already scaled by log2e/sqrt(hd)
    bf16x8 qah[CH], qal[CH];
    #pragma unroll
    for (int c = 0; c < CH; ++c) {
        const int k0 = c * 32 + lb * 8;
        bf16x8 vh = z8, vl = z8;
        if (k0 < hd) {
            const size_t o = hbq + (size_t)(q0 + lr) * hd + k0;
            vh = *(const bf16x8*)&Qh[o];
            vl = *(const bf16x8*)&Ql[o];
        }
        qah[c] = vh; qal[c] = vl;
    }

    const int q = q0 + lr;
    f32x4 acc2[NTP];
    #pragma unroll
    for (int tt = 0; tt < NTP; ++tt) acc2[tt] = (f32x4){0.f, 0.f, 0.f, 0.f};

    for (int cc = 0; cc < 4; ++cc) {
        const int colA = (half * 8 + cc * 2) * 32;
        const int colB = colA + 32;

        // ---- QK^T for both streams (4 tiles of 16 cols) ----
        f32x4 sA0 = {0.f,0.f,0.f,0.f}, sA1 = {0.f,0.f,0.f,0.f};
        f32x4 sB0 = {0.f,0.f,0.f,0.f}, sB1 = {0.f,0.f,0.f,0.f};
        #pragma unroll
        for (int c = 0; c < CH; ++c) {
            const int k0 = c * 32 + lb * 8;
            bf16x8 a0h=z8,a0l=z8,a1h=z8,a1l=z8,b0h=z8,b0l=z8,b1h=z8,b1l=z8;
            if (k0 < hd) {
                const size_t oA0 = hbq + (size_t)(colA + lr) * hd + k0;
                const size_t oA1 = hbq + (size_t)(colA + 16 + lr) * hd + k0;
                const size_t oB0 = hbq + (size_t)(colB + lr) * hd + k0;
                const size_t oB1 = hbq + (size_t)(colB + 16 + lr) * hd + k0;
                a0h = *(const bf16x8*)&Kh[oA0]; a0l = *(const bf16x8*)&Kl[oA0];
                a1h = *(const bf16x8*)&Kh[oA1]; a1l = *(const bf16x8*)&Kl[oA1];
                b0h = *(const bf16x8*)&Kh[oB0]; b0l = *(const bf16x8*)&Kl[oB0];
                b1h = *(const bf16x8*)&Kh[oB1]; b1l = *(const bf16x8*)&Kl[oB1];
            }
            sA0 = mfma16(a0h, qah[c], sA0);
            sB0 = mfma16(b0h, qah[c], sB0);
            sA1 = mfma16(a1h, qah[c], sA1);
            sB1 = mfma16(b1h, qah[c], sB1);
            sA0 = mfma16(a0l, qah[c], sA0);
            sB0 = mfma16(b0l, qah[c], sB0);
            sA1 = mfma16(a1l, qah[c], sA1);
            sB1 = mfma16(b1l, qah[c], sB1);
            sA0 = mfma16(a0h, qal[c], sA0);
            sB0 = mfma16(b0h, qal[c], sB0);
            sA1 = mfma16(a1h, qal[c], sA1);
            sB1 = mfma16(b1h, qal[c], sB1);
        }

        // ---- exp2 * ring-table -> packed bf16 -> per-stream LDS ----
        #pragma unroll
        for (int st = 0; st < 2; ++st) {
            ush* Pc = st ? PcB : PcA;
            const int colS = st ? colB : colA;
            #pragma unroll
            for (int t = 0; t < 2; ++t) {
                const f32x4 sv = st ? (t ? sB1 : sB0) : (t ? sA1 : sA0);
                const int kbase = colS + t * 16 + lb * 4;
                const int j0 = (kbase - q) & 511;
                float p[4];
                #pragma unroll
                for (int i = 0; i < 4; ++i)
                    p[i] = exp2f(sv[i]) * wtab[j0 + i];
                unsigned pk0, pk1;
                asm("v_cvt_pk_bf16_f32 %0, %1, %2" : "=v"(pk0) : "v"(p[0]), "v"(p[1]));
                asm("v_cvt_pk_bf16_f32 %0, %1, %2" : "=v"(pk1) : "v"(p[2]), "v"(p[3]));
                uint2s pv; pv.x = pk0; pv.y = pk1;
                *(uint2s*)((char*)Pc + lr * 80 + t * 32 + lb * 8) = pv;
            }
        }

        // ---- PV for both streams (independent LDS reads, chained acc) ----
        const bf16x8 paA = *(const bf16x8*)((const char*)PcA + lr * 80 + lb * 16);
        const bf16x8 paB = *(const bf16x8*)((const char*)PcB + lr * 80 + lb * 16);
        #pragma unroll
        for (int tt = 0; tt < NTP; ++tt) {
            const size_t oA = hbv + (size_t)(tt * 16 + lr) * N_ + colA + lb * 8;
            const size_t oB = hbv + (size_t)(tt * 16 + lr) * N_ + colB + lb * 8;
            const bf16x8 vAh = *(const bf16x8*)&Vth[oA];
            const bf16x8 vAl = *(const bf16x8*)&Vtl[oA];
            const bf16x8 vBh = *(const bf16x8*)&Vth[oB];
            const bf16x8 vBl = *(const bf16x8*)&Vtl[oB];
            acc2[tt] = mfma16(paA, vAh, acc2[tt]);
            acc2[tt] = mfma16(paA, vAl, acc2[tt]);
            acc2[tt] = mfma16(paB, vBh, acc2[tt]);
            acc2[tt] = mfma16(paB, vBl, acc2[tt]);
        }
    }

    // cross-half combine (conflict-free [tt][i][lane] layout), 1 barrier
    if (half) {
        #pragma unroll
        for (int tt = 0; tt < NTP; ++tt)
            #pragma unroll
            for (int i = 0; i < 4; ++i)
                comb[((pair * NTP + tt) * 4 + i) * 64 + lane] = acc2[tt][i];
    }
    __syncthreads();
    if (!half) {
        #pragma unroll
        for (int tt = 0; tt < NTP; ++tt)
            #pragma unroll
            for (int i = 0; i < 4; ++i)
                acc2[tt][i] += comb[((pair * NTP + tt) * 4 + i) * 64 + lane];
        // l = ones-column of summed accumulator; redistribute per output row
        float linv[4];
        #pragma unroll
        for (int i = 0; i < 4; ++i)
            linv[i] = 1.0f / __shfl(acc2[TL][i], (lane & 48) | LRL);
        #pragma unroll
        for (int tt = 0; tt < NTP; ++tt)
            #pragma unroll
            for (int i = 0; i < 4; ++i) {
                const int rn = q0 + lb * 4 + i;
                const int tc = tt * 16 + lr;
                if (tc < hd)
                    O[((size_t)b * N_ + rn) * DM_ + d * ds + h * hd + tc] = acc2[tt][i] * linv[i];
            }
    }
}
#define DEF_ATTN(NAME, DD, BR)                                                \
__global__ __launch_bounds__(256) void NAME(                                  \
        const float* __restrict__ logits,                                     \
        const ush* __restrict__ Qh, const ush* __restrict__ Ql,               \
        const ush* __restrict__ Kh, const ush* __restrict__ Kl,               \
        const ush* __restrict__ Vth, const ush* __restrict__ Vtl,             \
        float* __restrict__ O) {                                              \
    __shared__ __align__(16) ush Pc[4 * 2 * 16 * 40];                         \
    __shared__ float wtab[516];                                               \
    __shared__ float comb[2560];                                              \
    if (sel_of(logits) != BR) return;                                         \
    attn_dev<DD>(blockIdx.x, threadIdx.x, Qh, Ql, Kh, Kl, Vth, Vtl, O,        \
                 Pc, wtab, comb);                                             \
}
DEF_ATTN(k_attn_1, 1, 0)
DEF_ATTN(k_attn_2, 2, 1)
DEF_ATTN(k_attn_4, 4, 2)
DEF_ATTN(k_attn_8, 8, 3)

// ---------------------------------------------------------------------------
// depth mix: F = einsum(mix, O) -> bf16 hi/lo
// ---------------------------------------------------------------------------
template<int D>
__device__ void mix_body(int bid, int tid, const float* __restrict__ fu,
                         const float* __restrict__ fv, const float* __restrict__ O,
                         ush* __restrict__ Fh, ush* __restrict__ Fl, float* mixs) {
    constexpr int ds = DM_ / D;
    constexpr int R = (D / 4 > 0) ? (D / 4) : 1;
    if (tid < D * D) {
        const int d = tid / D, f = tid % D;
        float m = 0.f;
        #pragma unroll
        for (int rr = 0; rr < R; ++rr) m += fu[d * R + rr] * fv[rr * D + f];
        mixs[tid] = m;
    }
    __syncthreads();
    const size_t idx = (size_t)bid * 256 + tid;
    const int dm = (int)(idx % DM_);
    const size_t bn = idx / DM_;
    const int d = dm / ds, s0 = dm % ds;
    const float* Ob = O + bn * DM_ + s0;
    float acc = 0.f;
    #pragma unroll
    for (int f = 0; f < D; ++f) acc += mixs[d * D + f] * Ob[(size_t)f * ds];
    const ush hh = f2bf(acc);
    Fh[idx] = hh; Fl[idx] = f2bf(acc - bf2f(hh));
}
__global__ __launch_bounds__(256) void k_mix(
        const float* __restrict__ logits,
        const float* __restrict__ fu0, const float* __restrict__ fv0,
        const float* __restrict__ fu1, const float* __restrict__ fv1,
        const float* __restrict__ fu2, const float* __restrict__ fv2,
        const float* __restrict__ fu3, const float* __restrict__ fv3,
        const float* __restrict__ O, ush* __restrict__ Fh, ush* __restrict__ Fl) {
    __shared__ float mixs[64];
    const int bid = blockIdx.x, tid = threadIdx.x;
    switch (sel_of(logits)) {
        case 0: mix_body<1>(bid, tid, fu0, fv0, O, Fh, Fl, mixs); break;
        case 1: mix_body<2>(bid, tid, fu1, fv1, O, Fh, Fl, mixs); break;
        case 2: mix_body<4>(bid, tid, fu2, fv2, O, Fh, Fl, mixs); break;
        case 3: mix_body<8>(bid, tid, fu3, fv3, O, Fh, Fl, mixs); break;
    }
}

// ---------------------------------------------------------------------------
// out = F @ wo — 32x64 tiles, grid 512
// ---------------------------------------------------------------------------
__global__ __launch_bounds__(256) void k_wo(
        const ush* __restrict__ Fh, const ush* __restrict__ Fl,
        const ush* __restrict__ wh, const ush* __restrict__ wl,
        float* __restrict__ out) {
    __shared__ ush lA[2][32 * 40];
    __shared__ ush lB[2][64 * 40];
    const int tid = threadIdx.x;
    const int bx = blockIdx.x & 15, by = blockIdx.x >> 4;
    const int row0 = by * 32, col0 = bx * 64;
    const int lane = tid & 63, w = tid >> 6;
    const int wq = w >> 1, wn = w & 1;
    const int lr = lane & 15, lb = lane >> 4;
    f32x4 acc[2] = {};

    for (int k0 = 0; k0 < DM_; k0 += 32) {
        {
            const int half = tid >> 7, t2 = tid & 127;
            const int srow = t2 >> 2, scg = t2 & 3;
            const ush* src = half ? Fl : Fh;
            *(bf16x8*)&lA[half][srow * 40 + scg * 8] =
                *(const bf16x8*)&src[(size_t)(row0 + srow) * DM_ + k0 + scg * 8];
        }
        {
            const int srow = tid >> 2, scg = tid & 3;
            *(bf16x8*)&lB[0][srow * 40 + scg * 8] =
                *(const bf16x8*)&wh[(size_t)(col0 + srow) * DM_ + k0 + scg * 8];
            *(bf16x8*)&lB[1][srow * 40 + scg * 8] =
                *(const bf16x8*)&wl[(size_t)(col0 + srow) * DM_ + k0 + scg * 8];
        }
        __syncthreads();
        const int ar = wq * 16 + lr;
        const bf16x8 ah = *(const bf16x8*)&lA[0][ar * 40 + lb * 8];
        const bf16x8 al = *(const bf16x8*)&lA[1][ar * 40 + lb * 8];
        #pragma unroll
        for (int ng = 0; ng < 2; ++ng) {
            const int br = wn * 32 + ng * 16 + lr;
            const bf16x8 bh = *(const bf16x8*)&lB[0][br * 40 + lb * 8];
            const bf16x8 bl = *(const bf16x8*)&lB[1][br * 40 + lb * 8];
            acc[ng] = mfma16(ah, bh, acc[ng]);
            acc[ng] = mfma16(al, bh, acc[ng]);
            acc[ng] = mfma16(ah, bl, acc[ng]);
        }
        __syncthreads();
    }
    #pragma unroll
    for (int ng = 0; ng < 2; ++ng)
        #pragma unroll
        for (int i = 0; i < 4; ++i) {
            const int r = row0 + wq * 16 + lb * 4 + i;
            const int c = col0 + wn * 32 + ng * 16 + lr;
            out[(size_t)r * DM_ + c] = acc[ng][i];
        }
}

// ---------------------------------------------------------------------------
extern "C" void kernel_launch(void* const* d_in, const int* in_sizes, int n_in,
                              void* d_out, int out_size, void* d_ws, size_t ws_size,
                              hipStream_t stream) {
    const float* x      = (const float*)d_in[0];
    const float* logits = (const float*)d_in[1];
    float* out = (float*)d_out;

    char* p = (char*)d_ws;
    p += 256;
    const size_t MB = 1024 * 1024;
    ush* Qh = (ush*)p; p += 2 * MB;
    ush* Ql = (ush*)p; p += 2 * MB;
    ush* Kh = (ush*)p; p += 2 * MB;
    ush* Kl = (ush*)p; p += 2 * MB;
    ush* Vth = (ush*)p; p += 4 * MB;           // padded V^T
    ush* Vtl = (ush*)p; p += 4 * MB;
    float* O = (float*)p; p += 4 * MB;
    ush* xh = (ush*)p; p += 2 * MB;
    ush* xl = (ush*)p; p += 2 * MB;
    ush* wqh = (ush*)p; p += 6 * MB;
    ush* wql = (ush*)p; p += 6 * MB;
    ush* woh = (ush*)p; p += 2 * MB;
    ush* wol = (ush*)p; p += 2 * MB;
    ush* Fh = xh, *Fl = xl;   // k_mix writes after k_qkv consumed xh/xl

    k_prep<<<dim3(3072), dim3(256), 0, stream>>>(
        logits, x,
        (const float*)d_in[2], (const float*)d_in[7],
        (const float*)d_in[12], (const float*)d_in[17],
        (const float*)d_in[3], (const float*)d_in[8],
        (const float*)d_in[13], (const float*)d_in[18],
        (const float*)d_in[4], (const float*)d_in[9],
        (const float*)d_in[14], (const float*)d_in[19],
        xh, xl, wqh, wql, woh, wol, Vth, Vtl);
    k_qkv<<<dim3(768), dim3(256), 0, stream>>>(logits, xh, xl, wqh, wql,
                                               Qh, Ql, Kh, Kl, Vth, Vtl);
    k_attn_1<<<dim3(512),  dim3(256), 0, stream>>>(logits, Qh, Ql, Kh, Kl, Vth, Vtl, O);
    k_attn_2<<<dim3(1024), dim3(256), 0, stream>>>(logits, Qh, Ql, Kh, Kl, Vth, Vtl, O);
    k_attn_4<<<dim3(2048), dim3(256), 0, stream>>>(logits, Qh, Ql, Kh, Kl, Vth, Vtl, O);
    k_attn_8<<<dim3(4096), dim3(256), 0, stream>>>(logits, Qh, Ql, Kh, Kl, Vth, Vtl, O);
    k_mix<<<dim3(B_ * N_ * DM_ / 256), dim3(256), 0, stream>>>(
        logits,
        (const float*)d_in[5],  (const float*)d_in[6],
        (const float*)d_in[10], (const float*)d_in[11],
        (const float*)d_in[15], (const float*)d_in[16],
        (const float*)d_in[20], (const float*)d_in[21],
        O, Fh, Fl);
    k_wo<<<dim3(512), dim3(256), 0, stream>>>(Fh, Fl, woh, wol, out);
}

// Round 13
// 95.879 us; speedup vs baseline: 1.0358x; 1.0015x over previous
//
#include <hip/hip_runtime.h>

#define B_   2
#define N_   512
#define DM_  1024
#define H_   16
#define LAM_ 0.1f

typedef __attribute__((ext_vector_type(8))) short bf16x8;
typedef __attribute__((ext_vector_type(4))) float f32x4;
typedef unsigned short ush;
struct ush4 { ush x, y, z, w; };
struct uint2s { unsigned x, y; };

__device__ inline ush f2bf(float v) {
    union { float f; unsigned u; } c; c.f = v;
    unsigned r = c.u + 0x7FFF + ((c.u >> 16) & 1);
    return (ush)(r >> 16);
}
__device__ inline float bf2f(ush b) {
    union { float f; unsigned u; } c; c.u = ((unsigned)b) << 16; return c.f;
}
__device__ inline f32x4 mfma16(bf16x8 a, bf16x8 b, f32x4 c) {
    return __builtin_amdgcn_mfma_f32_16x16x32_bf16(a, b, c, 0, 0, 0);
}
// jnp.argmax semantics (first max wins); uniform -> scalar loads
__device__ inline int sel_of(const float* __restrict__ lg) {
    float b = lg[0]; int s = 0;
    if (lg[1] > b) { b = lg[1]; s = 1; }
    if (lg[2] > b) { b = lg[2]; s = 2; }
    if (lg[3] > b) { b = lg[3]; s = 3; }
    return s;
}

// V^T padded stride per head: data rows [0,hd), ones row at hd, zeros to PT
template<int HD> struct vpad_t { static constexpr int PT = (HD >= 16) ? HD + 16 : 16; };

// ---------------------------------------------------------------------------
// fused prep. Region map (256-thread blocks):
//   [0,    1024): x+pe -> bf16 hi/lo, float4-vectorized
//   [1024, 1792): wqkv transpose, 64x64 LDS tiles
//   [1792, 2048): wo transpose, 64x64 LDS tiles
//   [2048, 3072): V^T pad fill (ones row at hd, zeros above)
// ---------------------------------------------------------------------------
template<int D>
__device__ void prep_wt_tile(int bT, int tid, const float* __restrict__ w,
                             ush* __restrict__ wh, ush* __restrict__ wl,
                             float (*lds)[65]) {
    constexpr int ds = DM_ / D;
    constexpr int tpr = 3 * ds / 64;
    constexpr int tpc = ds / 64;
    constexpr int tpd = tpr * tpc;
    if (bT >= D * tpd) return;
    const int d = bT / tpd, rem = bT % tpd;
    const int tr = rem / tpr, tc = rem % tpr;
    const float* src = w + (size_t)d * ds * 3 * ds;
    ush* dsth = wh + (size_t)d * 3 * ds * ds;
    ush* dstl = wl + (size_t)d * 3 * ds * ds;
    const int c = tid & 63, r0 = tid >> 6;
    #pragma unroll
    for (int j = 0; j < 16; ++j) {
        const int r = j * 4 + r0;
        lds[r][c] = src[(size_t)(tr * 64 + r) * (3 * ds) + tc * 64 + c];
    }
    __syncthreads();
    #pragma unroll
    for (int j = 0; j < 16; ++j) {
        const int r = j * 4 + r0;
        const float v = lds[c][r];
        const size_t o = (size_t)(tc * 64 + r) * ds + tr * 64 + c;
        const ush h = f2bf(v);
        dsth[o] = h; dstl[o] = f2bf(v - bf2f(h));
    }
}
template<int D>
__device__ void prep_vpad(int bT, int tid, ush* __restrict__ Vth, ush* __restrict__ Vtl) {
    constexpr int ds = DM_ / D, hd = ds / H_;
    constexpr int PT = vpad_t<hd>::PT;
    constexpr int NH = B_ * D * H_;
    constexpr int PR = PT - hd;
    constexpr int TOT = NH * PR * (N_ / 4);
    const int g = bT * 256 + tid;
    if (g >= TOT) return;
    constexpr int perh = PR * (N_ / 4);
    const int head = g / perh, rem = g % perh;
    const int r = hd + rem / (N_ / 4), n4 = (rem % (N_ / 4)) * 4;
    const size_t o = ((size_t)head * PT + r) * N_ + n4;
    const ush one = (r == hd) ? (ush)0x3F80 : (ush)0;
    ush4 hv; hv.x = one; hv.y = one; hv.z = one; hv.w = one;
    ush4 zv; zv.x = 0; zv.y = 0; zv.z = 0; zv.w = 0;
    *(ush4*)&Vth[o] = hv;
    *(ush4*)&Vtl[o] = zv;
}
__global__ __launch_bounds__(256) void k_prep(
        const float* __restrict__ logits, const float* __restrict__ x,
        const float* __restrict__ pe0, const float* __restrict__ pe1,
        const float* __restrict__ pe2, const float* __restrict__ pe3,
        const float* __restrict__ w0, const float* __restrict__ w1,
        const float* __restrict__ w2, const float* __restrict__ w3,
        const float* __restrict__ wo0, const float* __restrict__ wo1,
        const float* __restrict__ wo2, const float* __restrict__ wo3,
        ush* __restrict__ xh, ush* __restrict__ xl,
        ush* __restrict__ wqh, ush* __restrict__ wql,
        ush* __restrict__ woh, ush* __restrict__ wol,
        ush* __restrict__ Vth, ush* __restrict__ Vtl) {
    __shared__ float lds[64][65];
    const int s = sel_of(logits);
    const int bid = blockIdx.x, tid = threadIdx.x;
    if (bid < 1024) {
        const float* pe = (s == 0) ? pe0 : (s == 1) ? pe1 : (s == 2) ? pe2 : pe3;
        const size_t i0 = ((size_t)bid * 256 + tid) * 4;
        const float4 xv = *(const float4*)&x[i0];
        const float4 pv = *(const float4*)&pe[i0 & ((size_t)N_ * DM_ - 1)];
        ush4 h4, l4;
        float v;
        v = xv.x + pv.x; h4.x = f2bf(v); l4.x = f2bf(v - bf2f(h4.x));
        v = xv.y + pv.y; h4.y = f2bf(v); l4.y = f2bf(v - bf2f(h4.y));
        v = xv.z + pv.z; h4.z = f2bf(v); l4.z = f2bf(v - bf2f(h4.z));
        v = xv.w + pv.w; h4.w = f2bf(v); l4.w = f2bf(v - bf2f(h4.w));
        *(ush4*)&xh[i0] = h4;
        *(ush4*)&xl[i0] = l4;
    } else if (bid < 1792) {
        const int bT = bid - 1024;
        switch (s) {
            case 0: prep_wt_tile<1>(bT, tid, w0, wqh, wql, lds); break;
            case 1: prep_wt_tile<2>(bT, tid, w1, wqh, wql, lds); break;
            case 2: prep_wt_tile<4>(bT, tid, w2, wqh, wql, lds); break;
            case 3: prep_wt_tile<8>(bT, tid, w3, wqh, wql, lds); break;
        }
    } else if (bid < 2048) {
        const float* w = (s == 0) ? wo0 : (s == 1) ? wo1 : (s == 2) ? wo2 : wo3;
        const int bT = bid - 1792;
        const int tr = bT >> 4, tc = bT & 15;
        const int c = tid & 63, r0 = tid >> 6;
        #pragma unroll
        for (int j = 0; j < 16; ++j) {
            const int r = j * 4 + r0;
            lds[r][c] = w[(size_t)(tr * 64 + r) * DM_ + tc * 64 + c];
        }
        __syncthreads();
        #pragma unroll
        for (int j = 0; j < 16; ++j) {
            const int r = j * 4 + r0;
            const float v = lds[c][r];
            const size_t o = (size_t)(tc * 64 + r) * DM_ + tr * 64 + c;
            const ush h = f2bf(v);
            woh[o] = h; wol[o] = f2bf(v - bf2f(h));
        }
    } else {
        const int bT = bid - 2048;
        switch (s) {
            case 0: prep_vpad<1>(bT, tid, Vth, Vtl); break;
            case 1: prep_vpad<2>(bT, tid, Vth, Vtl); break;
            case 2: prep_vpad<4>(bT, tid, Vth, Vtl); break;
            case 3: prep_vpad<8>(bT, tid, Vth, Vtl); break;
        }
    }
}

// ---------------------------------------------------------------------------
// Split-bf16 MFMA GEMM core (64x64 tile, BK=32, 4 waves) — used by k_qkv
// ---------------------------------------------------------------------------
template<int KD>
__device__ void gemm_core(const ush* __restrict__ Ah, const ush* __restrict__ Al, int lda,
                          const ush* __restrict__ Bh, const ush* __restrict__ Bl, int ldb,
                          int row0, int col0, int tid, ush* lds, f32x4 acc[2][2]) {
    ush* lAh = lds; ush* lAl = lds + 2560; ush* lBh = lds + 5120; ush* lBl = lds + 7680;
    const int srow = tid >> 2, scg = tid & 3;
    const int lane = tid & 63, w = tid >> 6;
    const int wm = w >> 1, wn = w & 1;
    const int lr = lane & 15, lb = lane >> 4;

    for (int k0 = 0; k0 < KD; k0 += 32) {
        *(bf16x8*)&lAh[srow * 40 + scg * 8] =
            *(const bf16x8*)&Ah[(size_t)(row0 + srow) * lda + k0 + scg * 8];
        *(bf16x8*)&lAl[srow * 40 + scg * 8] =
            *(const bf16x8*)&Al[(size_t)(row0 + srow) * lda + k0 + scg * 8];
        *(bf16x8*)&lBh[srow * 40 + scg * 8] =
            *(const bf16x8*)&Bh[(size_t)(col0 + srow) * ldb + k0 + scg * 8];
        *(bf16x8*)&lBl[srow * 40 + scg * 8] =
            *(const bf16x8*)&Bl[(size_t)(col0 + srow) * ldb + k0 + scg * 8];
        __syncthreads();
        bf16x8 ah[2], al[2], bh[2], bl[2];
        #pragma unroll
        for (int mg = 0; mg < 2; ++mg) {
            const int r = wm * 32 + mg * 16 + lr;
            ah[mg] = *(const bf16x8*)&lAh[r * 40 + lb * 8];
            al[mg] = *(const bf16x8*)&lAl[r * 40 + lb * 8];
        }
        #pragma unroll
        for (int ng = 0; ng < 2; ++ng) {
            const int r = wn * 32 + ng * 16 + lr;
            bh[ng] = *(const bf16x8*)&lBh[r * 40 + lb * 8];
            bl[ng] = *(const bf16x8*)&lBl[r * 40 + lb * 8];
        }
        #pragma unroll
        for (int mg = 0; mg < 2; ++mg)
            #pragma unroll
            for (int ng = 0; ng < 2; ++ng) {
                acc[mg][ng] = mfma16(ah[mg], bh[ng], acc[mg][ng]);
                acc[mg][ng] = mfma16(al[mg], bh[ng], acc[mg][ng]);
                acc[mg][ng] = mfma16(ah[mg], bl[ng], acc[mg][ng]);
            }
        __syncthreads();
    }
}

// ---------------------------------------------------------------------------
// qkv GEMM; epilogue: Q (PRE-SCALED by log2e/sqrt(hd)) and K as bf16 hi/lo
// [head][n][hd]; V TRANSPOSED bf16 hi/lo into padded [head][PT][n]
// ---------------------------------------------------------------------------
template<int D>
__device__ void qkv_body(int bid, int tid,
                         const ush* __restrict__ xh, const ush* __restrict__ xl,
                         const ush* __restrict__ wh, const ush* __restrict__ wl,
                         ush* __restrict__ Qh, ush* __restrict__ Ql,
                         ush* __restrict__ Kh, ush* __restrict__ Kl,
                         ush* __restrict__ Vth, ush* __restrict__ Vtl, ush* lds) {
    constexpr int ds = DM_ / D;
    constexpr int hd = ds / H_;
    constexpr int PT = vpad_t<hd>::PT;
    constexpr int nx = 3 * ds / 64;
    const int bx = bid % nx, by = (bid / nx) & 7, bz = bid / (nx * 8);
    const int b = bz / D, d = bz % D;
    const int row0 = by * 64, col0 = bx * 64;
    const float SCQ = 1.44269504f * rsqrtf((float)hd);

    f32x4 acc[2][2] = {};
    gemm_core<ds>(xh + (size_t)b * N_ * DM_ + d * ds, xl + (size_t)b * N_ * DM_ + d * ds, DM_,
                  wh + (size_t)d * 3 * ds * ds, wl + (size_t)d * 3 * ds * ds, ds,
                  row0, col0, tid, lds, acc);

    const int lane = tid & 63, w = tid >> 6;
    const int wm = w >> 1, wn = w & 1;
    const int lr = lane & 15, lb = lane >> 4;
    #pragma unroll
    for (int mg = 0; mg < 2; ++mg)
        #pragma unroll
        for (int ng = 0; ng < 2; ++ng) {
            const int n0 = row0 + wm * 32 + mg * 16 + lb * 4;
            const int e  = col0 + wn * 32 + ng * 16 + lr;
            const int part = e / ds, ep = e % ds;
            const int h = ep / hd, t = ep % hd;
            const size_t head = ((size_t)b * D + d) * H_ + h;
            if (part == 2) {
                ush4 h4, l4;
                const float v0 = acc[mg][ng][0], v1 = acc[mg][ng][1];
                const float v2 = acc[mg][ng][2], v3 = acc[mg][ng][3];
                h4.x = f2bf(v0); l4.x = f2bf(v0 - bf2f(h4.x));
                h4.y = f2bf(v1); l4.y = f2bf(v1 - bf2f(h4.y));
                h4.z = f2bf(v2); l4.z = f2bf(v2 - bf2f(h4.z));
                h4.w = f2bf(v3); l4.w = f2bf(v3 - bf2f(h4.w));
                const size_t o = (head * PT + t) * N_ + n0;
                *(ush4*)&Vth[o] = h4;
                *(ush4*)&Vtl[o] = l4;
            } else {
                #pragma unroll
                for (int i = 0; i < 4; ++i) {
                    const size_t o = (head * N_ + n0 + i) * hd + t;
                    float v = acc[mg][ng][i];
                    if (part == 0) v *= SCQ;
                    const ush hh = f2bf(v), ll = f2bf(v - bf2f(hh));
                    if (part == 0) { Qh[o] = hh; Ql[o] = ll; }
                    else           { Kh[o] = hh; Kl[o] = ll; }
                }
            }
        }
}
__global__ __launch_bounds__(256) void k_qkv(
        const float* __restrict__ logits,
        const ush* __restrict__ xh, const ush* __restrict__ xl,
        const ush* __restrict__ wh, const ush* __restrict__ wl,
        ush* __restrict__ Qh, ush* __restrict__ Ql,
        ush* __restrict__ Kh, ush* __restrict__ Kl,
        ush* __restrict__ Vth, ush* __restrict__ Vtl) {
    __shared__ ush lds[4 * 2560];
    const int bid = blockIdx.x, tid = threadIdx.x;
    switch (sel_of(logits)) {
        case 0: qkv_body<1>(bid, tid, xh, xl, wh, wl, Qh, Ql, Kh, Kl, Vth, Vtl, lds); break;
        case 1: qkv_body<2>(bid, tid, xh, xl, wh, wl, Qh, Ql, Kh, Kl, Vth, Vtl, lds); break;
        case 2: qkv_body<4>(bid, tid, xh, xl, wh, wl, Qh, Ql, Kh, Kl, Vth, Vtl, lds); break;
        case 3: qkv_body<8>(bid, tid, xh, xl, wh, wl, Qh, Ql, Kh, Kl, Vth, Vtl, lds); break;
    }
}

// ---------------------------------------------------------------------------
// MFMA attention v10: per-D kernels; block = 4 waves = 2 q-tiles x 2 k-halves.
// SOFTWARE-PIPELINED chunk loop: K/V fragments for chunk c+1 prefetched into
// registers while chunk c computes (fully unrolled -> SSA double buffers, no
// scratch). Removes global-load latency from the per-chunk critical path
// (round-12 counters: chunk-throughput-bound at ~420cyc with both pipes idle).
// m=0 softmax via exp2 + ring-bias LDS table, pre-scaled Q, denominator =
// PV ones-column; s_setprio around MFMA clusters; cross-half combine, 1 barrier.
// ---------------------------------------------------------------------------
template<int D>
__device__ void attn_dev(int bid, int tid,
        const ush* __restrict__ Qh, const ush* __restrict__ Ql,
        const ush* __restrict__ Kh, const ush* __restrict__ Kl,
        const ush* __restrict__ Vth, const ush* __restrict__ Vtl,
        float* __restrict__ O) {
    constexpr int ds = DM_ / D, hd = ds / H_;
    constexpr int CH  = (hd >= 64) ? 2 : 1;
    constexpr int NTP = (hd >= 16) ? hd / 16 + 1 : 1;
    constexpr int PT  = vpad_t<hd>::PT;
    constexpr int TL  = hd / 16;
    constexpr int LRL = hd % 16;
    constexpr int NBLK = B_ * D * H_ * 16;   // 2 q-tiles per block
    const float RB2 = LAM_ * (2.0f / N_) * 1.44269504f;

    __shared__ __align__(16) ush Pall[4 * 640];        // 16x40 ush per wave
    __shared__ float wtab[516];
    __shared__ float comb[2 * NTP * 4 * 64];

    // ring-bias table: wtab[j] = exp2(-RB2 * ring(j)), padded 4 for wrap
    for (int j = tid; j < 516; j += 256) {
        const int jj = j & 511;
        const int ring = (jj < 512 - jj) ? jj : 512 - jj;
        wtab[j] = exp2f(-RB2 * (float)ring);
    }
    __syncthreads();

    const int bidr = (bid & 7) * (NBLK / 8) + (bid >> 3);
    const int w = tid >> 6, lane = tid & 63;
    const int pair = w >> 1, half = w & 1;
    const int gt = bidr * 2 + pair;          // global q-tile
    const int head = gt >> 5, qt = gt & 31;
    const int h = head % H_, d = (head / H_) % D, b = head / (H_ * D);
    const int q0 = qt * 16;
    const size_t hbq = (size_t)head * N_ * hd;
    const size_t hbv = (size_t)head * PT * N_;
    const int lr = lane & 15, lb = lane >> 4;
    ush* Pc = Pall + w * 640;
    const bf16x8 z8 = {0, 0, 0, 0, 0, 0, 0, 0};

    // Q fragment (B-operand), already scaled by log2e/sqrt(hd)
    bf16x8 qah[CH], qal[CH];
    #pragma unroll
    for (int c = 0; c < CH; ++c) {
        const int k0 = c * 32 + lb * 8;
        bf16x8 vh = z8, vl = z8;
        if (k0 < hd) {
            const size_t o = hbq + (size_t)(q0 + lr) * hd + k0;
            vh = *(const bf16x8*)&Qh[o];
            vl = *(const bf16x8*)&Ql[o];
        }
        qah[c] = vh; qal[c] = vl;
    }

    const int q = q0 + lr;
    f32x4 acc2[NTP];
    #pragma unroll
    for (int tt = 0; tt < NTP; ++tt) acc2[tt] = (f32x4){0.f, 0.f, 0.f, 0.f};

    auto loadK = [&](int col, bf16x8 (&h0)[CH], bf16x8 (&l0)[CH],
                     bf16x8 (&h1)[CH], bf16x8 (&l1)[CH]) {
        #pragma unroll
        for (int c = 0; c < CH; ++c) {
            const int k0 = c * 32 + lb * 8;
            h0[c] = z8; l0[c] = z8; h1[c] = z8; l1[c] = z8;
            if (k0 < hd) {
                const size_t o0 = hbq + (size_t)(col + lr) * hd + k0;
                const size_t o1 = hbq + (size_t)(col + 16 + lr) * hd + k0;
                h0[c] = *(const bf16x8*)&Kh[o0]; l0[c] = *(const bf16x8*)&Kl[o0];
                h1[c] = *(const bf16x8*)&Kh[o1]; l1[c] = *(const bf16x8*)&Kl[o1];
            }
        }
    };
    auto loadV = [&](int col, bf16x8 (&vh)[NTP], bf16x8 (&vl)[NTP]) {
        #pragma unroll
        for (int tt = 0; tt < NTP; ++tt) {
            const size_t o = hbv + (size_t)(tt * 16 + lr) * N_ + col + lb * 8;
            vh[tt] = *(const bf16x8*)&Vth[o];
            vl[tt] = *(const bf16x8*)&Vtl[o];
        }
    };

    // pipeline: prefetch chunk 0
    bf16x8 kh0[CH], kl0[CH], kh1[CH], kl1[CH], vvh[NTP], vvl[NTP];
    loadK(half * 256, kh0, kl0, kh1, kl1);
    loadV(half * 256, vvh, vvl);

    #pragma unroll
    for (int c = 0; c < 8; ++c) {
        const int col0 = half * 256 + c * 32;

        // issue next chunk's loads first (hide latency under compute)
        bf16x8 nkh0[CH], nkl0[CH], nkh1[CH], nkl1[CH], nvh[NTP], nvl[NTP];
        if (c < 7) {
            loadK(col0 + 32, nkh0, nkl0, nkh1, nkl1);
            loadV(col0 + 32, nvh, nvl);
        }

        // QK^T for 2 tiles (32 k-cols), log2-scaled
        f32x4 s0 = {0.f, 0.f, 0.f, 0.f}, s1 = {0.f, 0.f, 0.f, 0.f};
        __builtin_amdgcn_s_setprio(1);
        #pragma unroll
        for (int cc = 0; cc < CH; ++cc) {
            s0 = mfma16(kh0[cc], qah[cc], s0);
            s1 = mfma16(kh1[cc], qah[cc], s1);
            s0 = mfma16(kl0[cc], qah[cc], s0);
            s1 = mfma16(kl1[cc], qah[cc], s1);
            s0 = mfma16(kh0[cc], qal[cc], s0);
            s1 = mfma16(kh1[cc], qal[cc], s1);
        }
        __builtin_amdgcn_s_setprio(0);

        // p = exp2(s) * wtab[(k-q)&511]; packed bf16 -> LDS
        #pragma unroll
        for (int t = 0; t < 2; ++t) {
            const f32x4 sv = t ? s1 : s0;
            const int kbase = col0 + t * 16 + lb * 4;
            const int j0 = (kbase - q) & 511;
            float p[4];
            #pragma unroll
            for (int i = 0; i < 4; ++i)
                p[i] = exp2f(sv[i]) * wtab[j0 + i];
            unsigned pk0, pk1;
            asm("v_cvt_pk_bf16_f32 %0, %1, %2" : "=v"(pk0) : "v"(p[0]), "v"(p[1]));
            asm("v_cvt_pk_bf16_f32 %0, %1, %2" : "=v"(pk1) : "v"(p[2]), "v"(p[3]));
            uint2s pv; pv.x = pk0; pv.y = pk1;
            *(uint2s*)((char*)Pc + lr * 80 + t * 32 + lb * 8) = pv;
        }

        // PV for this chunk (V already in registers)
        const bf16x8 pa = *(const bf16x8*)((const char*)Pc + lr * 80 + lb * 16);
        __builtin_amdgcn_s_setprio(1);
        #pragma unroll
        for (int tt = 0; tt < NTP; ++tt) {
            acc2[tt] = mfma16(pa, vvh[tt], acc2[tt]);
            acc2[tt] = mfma16(pa, vvl[tt], acc2[tt]);
        }
        __builtin_amdgcn_s_setprio(0);

        // rotate double buffers (SSA under full unroll)
        if (c < 7) {
            #pragma unroll
            for (int u = 0; u < CH; ++u) {
                kh0[u] = nkh0[u]; kl0[u] = nkl0[u];
                kh1[u] = nkh1[u]; kl1[u] = nkl1[u];
            }
            #pragma unroll
            for (int u = 0; u < NTP; ++u) { vvh[u] = nvh[u]; vvl[u] = nvl[u]; }
        }
    }

    // cross-half combine (conflict-free [tt][i][lane] layout), 1 barrier
    if (half) {
        #pragma unroll
        for (int tt = 0; tt < NTP; ++tt)
            #pragma unroll
            for (int i = 0; i < 4; ++i)
                comb[((pair * NTP + tt) * 4 + i) * 64 + lane] = acc2[tt][i];
    }
    __syncthreads();
    if (!half) {
        #pragma unroll
        for (int tt = 0; tt < NTP; ++tt)
            #pragma unroll
            for (int i = 0; i < 4; ++i)
                acc2[tt][i] += comb[((pair * NTP + tt) * 4 + i) * 64 + lane];
        // l = ones-column of summed accumulator; redistribute per output row
        float linv[4];
        #pragma unroll
        for (int i = 0; i < 4; ++i)
            linv[i] = 1.0f / __shfl(acc2[TL][i], (lane & 48) | LRL);
        #pragma unroll
        for (int tt = 0; tt < NTP; ++tt)
            #pragma unroll
            for (int i = 0; i < 4; ++i) {
                const int rn = q0 + lb * 4 + i;
                const int tc = tt * 16 + lr;
                if (tc < hd)
                    O[((size_t)b * N_ + rn) * DM_ + d * ds + h * hd + tc] = acc2[tt][i] * linv[i];
            }
    }
}
#define DEF_ATTN(NAME, DD, BR)                                                \
__global__ __launch_bounds__(256) void NAME(                                  \
        const float* __restrict__ logits,                                     \
        const ush* __restrict__ Qh, const ush* __restrict__ Ql,               \
        const ush* __restrict__ Kh, const ush* __restrict__ Kl,               \
        const ush* __restrict__ Vth, const ush* __restrict__ Vtl,             \
        float* __restrict__ O) {                                              \
    if (sel_of(logits) != BR) return;                                         \
    attn_dev<DD>(blockIdx.x, threadIdx.x, Qh, Ql, Kh, Kl, Vth, Vtl, O);       \
}
DEF_ATTN(k_attn_1, 1, 0)
DEF_ATTN(k_attn_2, 2, 1)
DEF_ATTN(k_attn_4, 4, 2)
DEF_ATTN(k_attn_8, 8, 3)

// ---------------------------------------------------------------------------
// depth mix: F = einsum(mix, O) -> bf16 hi/lo
// ---------------------------------------------------------------------------
template<int D>
__device__ void mix_body(int bid, int tid, const float* __restrict__ fu,
                         const float* __restrict__ fv, const float* __restrict__ O,
                         ush* __restrict__ Fh, ush* __restrict__ Fl, float* mixs) {
    constexpr int ds = DM_ / D;
    constexpr int R = (D / 4 > 0) ? (D / 4) : 1;
    if (tid < D * D) {
        const int d = tid / D, f = tid % D;
        float m = 0.f;
        #pragma unroll
        for (int rr = 0; rr < R; ++rr) m += fu[d * R + rr] * fv[rr * D + f];
        mixs[tid] = m;
    }
    __syncthreads();
    const size_t idx = (size_t)bid * 256 + tid;
    const int dm = (int)(idx % DM_);
    const size_t bn = idx / DM_;
    const int d = dm / ds, s0 = dm % ds;
    const float* Ob = O + bn * DM_ + s0;
    float acc = 0.f;
    #pragma unroll
    for (int f = 0; f < D; ++f) acc += mixs[d * D + f] * Ob[(size_t)f * ds];
    const ush hh = f2bf(acc);
    Fh[idx] = hh; Fl[idx] = f2bf(acc - bf2f(hh));
}
__global__ __launch_bounds__(256) void k_mix(
        const float* __restrict__ logits,
        const float* __restrict__ fu0, const float* __restrict__ fv0,
        const float* __restrict__ fu1, const float* __restrict__ fv1,
        const float* __restrict__ fu2, const float* __restrict__ fv2,
        const float* __restrict__ fu3, const float* __restrict__ fv3,
        const float* __restrict__ O, ush* __restrict__ Fh, ush* __restrict__ Fl) {
    __shared__ float mixs[64];
    const int bid = blockIdx.x, tid = threadIdx.x;
    switch (sel_of(logits)) {
        case 0: mix_body<1>(bid, tid, fu0, fv0, O, Fh, Fl, mixs); break;
        case 1: mix_body<2>(bid, tid, fu1, fv1, O, Fh, Fl, mixs); break;
        case 2: mix_body<4>(bid, tid, fu2, fv2, O, Fh, Fl, mixs); break;
        case 3: mix_body<8>(bid, tid, fu3, fv3, O, Fh, Fl, mixs); break;
    }
}

// ---------------------------------------------------------------------------
// out = F @ wo — 32x64 tiles, grid 512
// ---------------------------------------------------------------------------
__global__ __launch_bounds__(256) void k_wo(
        const ush* __restrict__ Fh, const ush* __restrict__ Fl,
        const ush* __restrict__ wh, const ush* __restrict__ wl,
        float* __restrict__ out) {
    __shared__ ush lA[2][32 * 40];
    __shared__ ush lB[2][64 * 40];
    const int tid = threadIdx.x;
    const int bx = blockIdx.x & 15, by = blockIdx.x >> 4;
    const int row0 = by * 32, col0 = bx * 64;
    const int lane = tid & 63, w = tid >> 6;
    const int wq = w >> 1, wn = w & 1;
    const int lr = lane & 15, lb = lane >> 4;
    f32x4 acc[2] = {};

    for (int k0 = 0; k0 < DM_; k0 += 32) {
        {
            const int half = tid >> 7, t2 = tid & 127;
            const int srow = t2 >> 2, scg = t2 & 3;
            const ush* src = half ? Fl : Fh;
            *(bf16x8*)&lA[half][srow * 40 + scg * 8] =
                *(const bf16x8*)&src[(size_t)(row0 + srow) * DM_ + k0 + scg * 8];
        }
        {
            const int srow = tid >> 2, scg = tid & 3;
            *(bf16x8*)&lB[0][srow * 40 + scg * 8] =
                *(const bf16x8*)&wh[(size_t)(col0 + srow) * DM_ + k0 + scg * 8];
            *(bf16x8*)&lB[1][srow * 40 + scg * 8] =
                *(const bf16x8*)&wl[(size_t)(col0 + srow) * DM_ + k0 + scg * 8];
        }
        __syncthreads();
        const int ar = wq * 16 + lr;
        const bf16x8 ah = *(const bf16x8*)&lA[0][ar * 40 + lb * 8];
        const bf16x8 al = *(const bf16x8*)&lA[1][ar * 40 + lb * 8];
        #pragma unroll
        for (int ng = 0; ng < 2; ++ng) {
            const int br = wn * 32 + ng * 16 + lr;
            const bf16x8 bh = *(const bf16x8*)&lB[0][br * 40 + lb * 8];
            const bf16x8 bl = *(const bf16x8*)&lB[1][br * 40 + lb * 8];
            acc[ng] = mfma16(ah, bh, acc[ng]);
            acc[ng] = mfma16(al, bh, acc[ng]);
            acc[ng] = mfma16(ah, bl, acc[ng]);
        }
        __syncthreads();
    }
    #pragma unroll
    for (int ng = 0; ng < 2; ++ng)
        #pragma unroll
        for (int i = 0; i < 4; ++i) {
            const int r = row0 + wq * 16 + lb * 4 + i;
            const int c = col0 + wn * 32 + ng * 16 + lr;
            out[(size_t)r * DM_ + c] = acc[ng][i];
        }
}

// ---------------------------------------------------------------------------
extern "C" void kernel_launch(void* const* d_in, const int* in_sizes, int n_in,
                              void* d_out, int out_size, void* d_ws, size_t ws_size,
                              hipStream_t stream) {
    const float* x      = (const float*)d_in[0];
    const float* logits = (const float*)d_in[1];
    float* out = (float*)d_out;

    char* p = (char*)d_ws;
    p += 256;
    const size_t MB = 1024 * 1024;
    ush* Qh = (ush*)p; p += 2 * MB;
    ush* Ql = (ush*)p; p += 2 * MB;
    ush* Kh = (ush*)p; p += 2 * MB;
    ush* Kl = (ush*)p; p += 2 * MB;
    ush* Vth = (ush*)p; p += 4 * MB;           // padded V^T
    ush* Vtl = (ush*)p; p += 4 * MB;
    float* O = (float*)p; p += 4 * MB;
    ush* xh = (ush*)p; p += 2 * MB;
    ush* xl = (ush*)p; p += 2 * MB;
    ush* wqh = (ush*)p; p += 6 * MB;
    ush* wql = (ush*)p; p += 6 * MB;
    ush* woh = (ush*)p; p += 2 * MB;
    ush* wol = (ush*)p; p += 2 * MB;
    ush* Fh = xh, *Fl = xl;   // k_mix writes after k_qkv consumed xh/xl

    k_prep<<<dim3(3072), dim3(256), 0, stream>>>(
        logits, x,
        (const float*)d_in[2], (const float*)d_in[7],
        (const float*)d_in[12], (const float*)d_in[17],
        (const float*)d_in[3], (const float*)d_in[8],
        (const float*)d_in[13], (const float*)d_in[18],
        (const float*)d_in[4], (const float*)d_in[9],
        (const float*)d_in[14], (const float*)d_in[19],
        xh, xl, wqh, wql, woh, wol, Vth, Vtl);
    k_qkv<<<dim3(768), dim3(256), 0, stream>>>(logits, xh, xl, wqh, wql,
                                               Qh, Ql, Kh, Kl, Vth, Vtl);
    k_attn_1<<<dim3(512),  dim3(256), 0, stream>>>(logits, Qh, Ql, Kh, Kl, Vth, Vtl, O);
    k_attn_2<<<dim3(1024), dim3(256), 0, stream>>>(logits, Qh, Ql, Kh, Kl, Vth, Vtl, O);
    k_attn_4<<<dim3(2048), dim3(256), 0, stream>>>(logits, Qh, Ql, Kh, Kl, Vth, Vtl, O);
    k_attn_8<<<dim3(4096), dim3(256), 0, stream>>>(logits, Qh, Ql, Kh, Kl, Vth, Vtl, O);
    k_mix<<<dim3(B_ * N_ * DM_ / 256), dim3(256), 0, stream>>>(
        logits,
        (const float*)d_in[5],  (const float*)d_in[6],
        (const float*)d_in[10], (const float*)d_in[11],
        (const float*)d_in[15], (const float*)d_in[16],
        (const float*)d_in[20], (const float*)d_in[21],
        O, Fh, Fl);
    k_wo<<<dim3(512), dim3(256), 0, stream>>>(Fh, Fl, woh, wol, out);
}